// Round 3
// baseline (415.124 us; speedup 1.0000x reference)
//
#include <hip/hip_runtime.h>
#include <hip/hip_bf16.h>
#include <cstdint>

// ---------------------------------------------------------------------------
// InteractionMHA: dual cross-attention (2d<->3d) + Linear/GELU, variadic
// graphs flattened to [total=40960, D=256]. ALL I/O IS FLOAT32 (verified via
// in_npz_mb=79.6MB => fp32). Compute in bf16 MFMA with fp32 accum; convert
// fp32->bf16 at GEMM staging, store final output fp32.
//
// Per branch:
//   Q  = rep_q  @ Wq^T + bq          (gemm_kernel, fp32 in -> bf16 out)
//   K  = rep_kv @ Wk^T + bk          (gemm_kernel)
//   Vt = Wv @ rep_kv^T (+bv per row) (gemm_kernel, swapped operands ->
//                                     V stored TRANSPOSED [256][total])
//   out = gelu(softmax(Q K^T/16) V @ Wm^T + bm)  (attn_kernel, fused, fp32 out)
// ---------------------------------------------------------------------------

typedef short s16x8 __attribute__((ext_vector_type(8)));
typedef short s16x4 __attribute__((ext_vector_type(4)));
typedef float f32x4 __attribute__((ext_vector_type(4)));

__global__ void sentinel_kernel(float* out, float v) {
  if (threadIdx.x == 0 && blockIdx.x == 0) out[0] = v;
}

// offsets scan; self-validates num_atoms dtype (int32 vs int64).
__global__ void scan_kernel(const int* __restrict__ na, int* __restrict__ offs,
                            int B, int total, float* out) {
  if (threadIdx.x != 0 || blockIdx.x != 0) return;
  long long s = 0;
  for (int b = 0; b < B; ++b) s += na[b];
  if (s == (long long)total) {
    int acc = 0;
    for (int b = 0; b < B; ++b) { offs[b] = acc; acc += na[b]; }
    offs[B] = acc;
    return;
  }
  const long long* na64 = (const long long*)na;   // int64 fallback
  s = 0;
  for (int b = 0; b < B; ++b) s += na64[b];
  if (s == (long long)total) {
    int acc = 0;
    for (int b = 0; b < B; ++b) { offs[b] = acc; acc += (int)na64[b]; }
    offs[B] = acc;
    return;
  }
  for (int b = 0; b <= B; ++b) offs[b] = 0;       // neither: disable attn
  out[0] = 31337.0f;                              // sentinel: na unparseable
}

// fp32 -> bf16 elementwise (for Wm weights used by fused attention)
__global__ void cvt_kernel(const float* __restrict__ in, __bf16* __restrict__ out, int n) {
  int i = (blockIdx.x * 256 + threadIdx.x) * 4;
  if (i + 3 < n) {
    float4 f = *(const float4*)(in + i);
    out[i + 0] = (__bf16)f.x; out[i + 1] = (__bf16)f.y;
    out[i + 2] = (__bf16)f.z; out[i + 3] = (__bf16)f.w;
  }
}

// ---------- GEMM: C[M][N] = A[M][256] @ Bw[N][256]^T + bias (fp32->bf16) ---
// 128x128 tile, BK=32, 4 waves (2x2), each wave 64x64 = 4x4 frags of 16x16.
__global__ __launch_bounds__(256) void gemm_kernel(
    const float* __restrict__ A, const float* __restrict__ Bw,
    const float* __restrict__ bias, __bf16* __restrict__ C,
    int N, int biasRow)
{
  __shared__ __bf16 At[128 * 32];
  __shared__ __bf16 Bt[128 * 32];
  const int t = threadIdx.x;
  const int lane = t & 63, w = t >> 6;
  const int wr = w >> 1, wc = w & 1;
  const int l15 = lane & 15, l4 = lane >> 4;
  const int by = blockIdx.x, bx = blockIdx.y;

  f32x4 acc[4][4];
  for (int m = 0; m < 4; ++m)
    for (int nn = 0; nn < 4; ++nn) acc[m][nn] = (f32x4){0.f, 0.f, 0.f, 0.f};

  for (int kk = 0; kk < 256; kk += 32) {
    for (int j = 0; j < 2; ++j) {
      int c = t + j * 256;                 // 0..511 chunks of 8 elements
      int row = c >> 2, off0 = (c & 3) * 8;
      const float* ap = A + (size_t)(by * 128 + row) * 256 + kk + off0;
      const float* bp = Bw + (size_t)(bx * 128 + row) * 256 + kk + off0;
      float4 a0 = *(const float4*)ap, a1 = *(const float4*)(ap + 4);
      float4 b0 = *(const float4*)bp, b1 = *(const float4*)(bp + 4);
      union { s16x8 v; __bf16 e[8]; } pa, pb;
      pa.e[0] = (__bf16)a0.x; pa.e[1] = (__bf16)a0.y; pa.e[2] = (__bf16)a0.z; pa.e[3] = (__bf16)a0.w;
      pa.e[4] = (__bf16)a1.x; pa.e[5] = (__bf16)a1.y; pa.e[6] = (__bf16)a1.z; pa.e[7] = (__bf16)a1.w;
      pb.e[0] = (__bf16)b0.x; pb.e[1] = (__bf16)b0.y; pb.e[2] = (__bf16)b0.z; pb.e[3] = (__bf16)b0.w;
      pb.e[4] = (__bf16)b1.x; pb.e[5] = (__bf16)b1.y; pb.e[6] = (__bf16)b1.z; pb.e[7] = (__bf16)b1.w;
      *(s16x8*)(&At[row * 32 + off0]) = pa.v;
      *(s16x8*)(&Bt[row * 32 + off0]) = pb.v;
    }
    __syncthreads();
    s16x8 af[4], bfr[4];
    for (int m = 0; m < 4; ++m)
      af[m] = *(const s16x8*)(&At[(wr * 64 + m * 16 + l15) * 32 + l4 * 8]);
    for (int nn = 0; nn < 4; ++nn)
      bfr[nn] = *(const s16x8*)(&Bt[(wc * 64 + nn * 16 + l15) * 32 + l4 * 8]);
    for (int m = 0; m < 4; ++m)
      for (int nn = 0; nn < 4; ++nn)
        acc[m][nn] = __builtin_amdgcn_mfma_f32_16x16x32_bf16(af[m], bfr[nn], acc[m][nn], 0, 0, 0);
    __syncthreads();
  }

  for (int m = 0; m < 4; ++m) {
    int row0 = by * 128 + wr * 64 + m * 16 + l4 * 4;
    for (int nn = 0; nn < 4; ++nn) {
      int col = bx * 128 + wc * 64 + nn * 16 + l15;
      float bc = biasRow ? 0.f : bias[col];
      for (int r = 0; r < 4; ++r) {
        int row = row0 + r;
        float v = acc[m][nn][r] + (biasRow ? bias[row] : bc);
        C[(size_t)row * N + col] = (__bf16)v;
      }
    }
  }
}

// ---------- fused attention + output projection + GELU (fp32 out) ---------
// grid (graph, qtile64); 4 waves/block, each wave owns 16 query rows.
__global__ __launch_bounds__(256) void attn_kernel(
    const __bf16* __restrict__ Q, const __bf16* __restrict__ Km,
    const __bf16* __restrict__ Vt, const __bf16* __restrict__ Wm,
    const float* __restrict__ bm, float* __restrict__ Out,
    const int* __restrict__ offs, int total)
{
  const int g = blockIdx.x, qt = blockIdx.y;
  const int off = offs[g];
  const int n = offs[g + 1] - off;
  const int t = threadIdx.x, lane = t & 63, w = t >> 6;
  const int qbase = qt * 64 + w * 16;
  if (qbase >= n) return;                 // wave-local exit (no block barriers)
  const int l15 = lane & 15, l4 = lane >> 4;

  __shared__ __bf16 Slds[4][16][132];     // per-wave P tile, 16 q x 128 keys
  __shared__ __bf16 Xlds[4][16][256];     // per-wave X tile, XOR-swizzled 16B blocks

  // Q fragments for this wave's 16 rows (8 k-steps of 32)
  s16x8 qf[8];
  {
    int qr = qbase + l15; if (qr >= n) qr = n - 1;
    const __bf16* qp = Q + (size_t)(off + qr) * 256 + l4 * 8;
    for (int kk = 0; kk < 8; ++kk) qf[kk] = *(const s16x8*)(qp + kk * 32);
  }

  // S = Q K^T ; fixed 8 key-tiles (const-indexed regs), skip empty tiles
  f32x4 sacc[8];
  for (int i = 0; i < 8; ++i) sacc[i] = (f32x4){0.f, 0.f, 0.f, 0.f};
  for (int kt = 0; kt < 8; ++kt) {
    if (kt * 16 < n) {
      int kr = kt * 16 + l15; if (kr >= n) kr = n - 1;   // masked in softmax
      const __bf16* kp = Km + (size_t)(off + kr) * 256 + l4 * 8;
      for (int kk = 0; kk < 8; ++kk) {
        s16x8 kf = *(const s16x8*)(kp + kk * 32);
        sacc[kt] = __builtin_amdgcn_mfma_f32_16x16x32_bf16(qf[kk], kf, sacc[kt], 0, 0, 0);
      }
    }
  }

  // softmax over keys; row r of lane-group: q = (lane>>4)*4 + r
  const float scale = 0.0625f;            // 1/sqrt(256)
  for (int r = 0; r < 4; ++r) {
    float sv[8];
    float m = -1e30f;
    for (int kt = 0; kt < 8; ++kt) {
      int key = kt * 16 + l15;
      float v = (key < n) ? sacc[kt][r] * scale : -1e30f;
      sv[kt] = v;
      m = fmaxf(m, v);
    }
    for (int o = 1; o < 16; o <<= 1) m = fmaxf(m, __shfl_xor(m, o));
    float p[8], sum = 0.f;
    for (int kt = 0; kt < 8; ++kt) { p[kt] = __expf(sv[kt] - m); sum += p[kt]; }
    for (int o = 1; o < 16; o <<= 1) sum += __shfl_xor(sum, o);
    float inv = 1.f / sum;
    int q = l4 * 4 + r;
    for (int kt = 0; kt < 8; ++kt)        // masked keys store exact 0
      Slds[w][q][kt * 16 + l15] = (__bf16)(p[kt] * inv);
  }
  asm volatile("s_waitcnt lgkmcnt(0)" ::: "memory");
  __builtin_amdgcn_sched_barrier(0);

  // X[16][256] = P[16][128] @ V[128][256]; B-frag rows from transposed Vt
  f32x4 xacc[16];
  for (int i = 0; i < 16; ++i) xacc[i] = (f32x4){0.f, 0.f, 0.f, 0.f};
  for (int ks = 0; ks < 4; ++ks) {
    union { s16x8 v8; s16x4 v4[2]; } pa;
    pa.v4[0] = *(const s16x4*)(&Slds[w][l15][ks * 32 + l4 * 8]);
    pa.v4[1] = *(const s16x4*)(&Slds[w][l15][ks * 32 + l4 * 8 + 4]);
    int kc = off + ks * 32 + l4 * 8;
    if (kc > total - 8) kc = total - 8;   // clamp: P is 0 there, data finite
    for (int dt = 0; dt < 16; ++dt) {
      s16x8 vf = *(const s16x8*)(Vt + (size_t)(dt * 16 + l15) * total + kc);
      xacc[dt] = __builtin_amdgcn_mfma_f32_16x16x32_bf16(pa.v8, vf, xacc[dt], 0, 0, 0);
    }
  }

  // stage X into XOR-swizzled LDS (16B blocks, bijective per 8-row stripe)
  for (int dt = 0; dt < 16; ++dt) {
    int blk = (dt * 16 + l15) >> 3;
    for (int r = 0; r < 4; ++r) {
      int q = l4 * 4 + r;
      Xlds[w][q][((blk ^ (q & 7)) << 3) | (l15 & 7)] = (__bf16)xacc[dt][r];
    }
  }
  asm volatile("s_waitcnt lgkmcnt(0)" ::: "memory");
  __builtin_amdgcn_sched_barrier(0);

  // O[16][256] = X @ Wm^T; A-frags from Xlds, B-frags direct from bf16 Wm
  f32x4 oacc[16];
  for (int i = 0; i < 16; ++i) oacc[i] = (f32x4){0.f, 0.f, 0.f, 0.f};
  for (int ks = 0; ks < 8; ++ks) {
    s16x8 af = *(const s16x8*)(&Xlds[w][l15][((ks * 4 + l4) ^ (l15 & 7)) << 3]);
    const __bf16* wp = Wm + (size_t)l15 * 256 + ks * 32 + l4 * 8;
    for (int jt = 0; jt < 16; ++jt) {
      s16x8 bf = *(const s16x8*)(wp + (size_t)jt * 16 * 256);
      oacc[jt] = __builtin_amdgcn_mfma_f32_16x16x32_bf16(af, bf, oacc[jt], 0, 0, 0);
    }
  }

  // epilogue: +bias, exact GELU, store fp32
  for (int jt = 0; jt < 16; ++jt) {
    int col = jt * 16 + l15;
    float bb = bm[col];
    for (int r = 0; r < 4; ++r) {
      int q = l4 * 4 + r;
      if (qbase + q < n) {
        float v = oacc[jt][r] + bb;
        v = 0.5f * v * (1.0f + erff(v * 0.70710678f));
        Out[(size_t)(off + qbase + q) * 256 + col] = v;
      }
    }
  }
}

// ---------------------------------------------------------------------------
extern "C" void kernel_launch(void* const* d_in, const int* in_sizes, int n_in,
                              void* d_out, int out_size, void* d_ws, size_t ws_size,
                              hipStream_t stream) {
  const float* rep2d = (const float*)d_in[0];
  const float* rep3d = (const float*)d_in[1];
  const int*   na    = (const int*)d_in[2];
  const float* wq23 = (const float*)d_in[3];  const float* bq23 = (const float*)d_in[4];
  const float* wk23 = (const float*)d_in[5];  const float* bk23 = (const float*)d_in[6];
  const float* wv23 = (const float*)d_in[7];  const float* bv23 = (const float*)d_in[8];
  const float* wq32 = (const float*)d_in[9];  const float* bq32 = (const float*)d_in[10];
  const float* wk32 = (const float*)d_in[11]; const float* bk32 = (const float*)d_in[12];
  const float* wv32 = (const float*)d_in[13]; const float* bv32 = (const float*)d_in[14];
  const float* wm23 = (const float*)d_in[15]; const float* bm23 = (const float*)d_in[16];
  const float* wm32 = (const float*)d_in[17]; const float* bm32 = (const float*)d_in[18];

  const int B = in_sizes[2];
  const int total = in_sizes[0] / 256;           // 40960
  float* out = (float*)d_out;

  char* ws = (char*)d_ws;
  const size_t SZ = (size_t)total * 256 * sizeof(__bf16);  // 20.97 MB
  const size_t WMB = 65536 * sizeof(__bf16);               // 128 KB each
  const size_t need = 8192 + 2 * WMB + 3 * SZ;             // ~63.2 MB
  if (ws_size < need) {                          // sentinel: ws too small
    sentinel_kernel<<<1, 64, 0, stream>>>(out, 54321.0f);
    return;
  }
  int*    offs = (int*)ws;                       // [B+1]
  __bf16* WM0 = (__bf16*)(ws + 8192);
  __bf16* WM1 = (__bf16*)(ws + 8192 + WMB);
  __bf16* BQ  = (__bf16*)(ws + 8192 + 2 * WMB);
  __bf16* BK  = (__bf16*)(ws + 8192 + 2 * WMB + SZ);
  __bf16* BV  = (__bf16*)(ws + 8192 + 2 * WMB + 2 * SZ);   // transposed V [256][total]

  scan_kernel<<<1, 64, 0, stream>>>(na, offs, B, total, out);
  cvt_kernel<<<64, 256, 0, stream>>>(wm23, WM0, 65536);
  cvt_kernel<<<64, 256, 0, stream>>>(wm32, WM1, 65536);

  dim3 blk(256);
  dim3 gP(total / 128, 2);   // [total,256] gemms
  dim3 gV(2, total / 128);   // transposed-V gemm: M=256, N=total
  dim3 gA(B, 2);             // attention: (graph, qtile64)

  // branch 2d -> 3d (queries from 2d, keys/values from 3d)
  gemm_kernel<<<gP, blk, 0, stream>>>(rep2d, wq23, bq23, BQ, 256, 0);
  gemm_kernel<<<gP, blk, 0, stream>>>(rep3d, wk23, bk23, BK, 256, 0);
  gemm_kernel<<<gV, blk, 0, stream>>>(wv23, rep3d, bv23, BV, total, 1);
  attn_kernel<<<gA, blk, 0, stream>>>(BQ, BK, BV, WM0, bm23, out, offs, total);

  // branch 3d -> 2d (queries from 3d, keys/values from 2d)
  gemm_kernel<<<gP, blk, 0, stream>>>(rep3d, wq32, bq32, BQ, 256, 0);
  gemm_kernel<<<gP, blk, 0, stream>>>(rep2d, wk32, bk32, BK, 256, 0);
  gemm_kernel<<<gV, blk, 0, stream>>>(wv32, rep2d, bv32, BV, total, 1);
  attn_kernel<<<gA, blk, 0, stream>>>(BQ, BK, BV, WM1, bm32,
                                      out + (size_t)total * 256, offs, total);
}

// Round 4
// 272.877 us; speedup vs baseline: 1.5213x; 1.5213x over previous
//
#include <hip/hip_runtime.h>
#include <hip/hip_bf16.h>
#include <cstdint>

// ---------------------------------------------------------------------------
// InteractionMHA, fp32 I/O, bf16-MFMA compute.
// Per branch:
//   Q  = rep_q  @ Wq^T + bq           (gemm_kernel -> BQ bf16)
//   K  = rep_kv @ Wk^T + bk           (gemm_kernel -> BK bf16)
//   Vt = Wv @ rep_kv^T (+bv per row)  (gemm_kernel -> BV bf16, V transposed)
//   X  = softmax(Q K^T/16) V          (attn_kernel, per-graph block, X -> BQ in-place)
//   out = gelu(X @ Wm^T + bm)         (gemm_out, fp32 out)
//
// attn: 1 block/graph, 8 waves. K staged once in LDS (pad-264); P through the
// SAME LDS (union) after a barrier; PV split by d across waves (V read 1x).
// ---------------------------------------------------------------------------

typedef short s16x8 __attribute__((ext_vector_type(8)));
typedef float f32x4 __attribute__((ext_vector_type(4)));

__global__ void sentinel_kernel(float* out, float v) {
  if (threadIdx.x == 0 && blockIdx.x == 0) out[0] = v;
}

__global__ void scan_kernel(const int* __restrict__ na, int* __restrict__ offs,
                            int B, int total, float* out) {
  if (threadIdx.x != 0 || blockIdx.x != 0) return;
  long long s = 0;
  for (int b = 0; b < B; ++b) s += na[b];
  if (s == (long long)total) {
    int acc = 0;
    for (int b = 0; b < B; ++b) { offs[b] = acc; acc += na[b]; }
    offs[B] = acc;
    return;
  }
  const long long* na64 = (const long long*)na;
  s = 0;
  for (int b = 0; b < B; ++b) s += na64[b];
  if (s == (long long)total) {
    int acc = 0;
    for (int b = 0; b < B; ++b) { offs[b] = acc; acc += (int)na64[b]; }
    offs[B] = acc;
    return;
  }
  for (int b = 0; b <= B; ++b) offs[b] = 0;
  out[0] = 31337.0f;
}

// ---------- GEMM: C[M][N] = A[M][256] @ Bw[N][256]^T + bias (fp32->bf16) ---
__global__ __launch_bounds__(256) void gemm_kernel(
    const float* __restrict__ A, const float* __restrict__ Bw,
    const float* __restrict__ bias, __bf16* __restrict__ C,
    int N, int biasRow)
{
  __shared__ __bf16 At[128 * 32];
  __shared__ __bf16 Bt[128 * 32];
  const int t = threadIdx.x;
  const int lane = t & 63, w = t >> 6;
  const int wr = w >> 1, wc = w & 1;
  const int l15 = lane & 15, l4 = lane >> 4;
  const int by = blockIdx.x, bx = blockIdx.y;

  f32x4 acc[4][4];
  for (int m = 0; m < 4; ++m)
    for (int nn = 0; nn < 4; ++nn) acc[m][nn] = (f32x4){0.f, 0.f, 0.f, 0.f};

  for (int kk = 0; kk < 256; kk += 32) {
    for (int j = 0; j < 2; ++j) {
      int c = t + j * 256;
      int row = c >> 2, off0 = (c & 3) * 8;
      const float* ap = A + (size_t)(by * 128 + row) * 256 + kk + off0;
      const float* bp = Bw + (size_t)(bx * 128 + row) * 256 + kk + off0;
      float4 a0 = *(const float4*)ap, a1 = *(const float4*)(ap + 4);
      float4 b0 = *(const float4*)bp, b1 = *(const float4*)(bp + 4);
      union { s16x8 v; __bf16 e[8]; } pa, pb;
      pa.e[0] = (__bf16)a0.x; pa.e[1] = (__bf16)a0.y; pa.e[2] = (__bf16)a0.z; pa.e[3] = (__bf16)a0.w;
      pa.e[4] = (__bf16)a1.x; pa.e[5] = (__bf16)a1.y; pa.e[6] = (__bf16)a1.z; pa.e[7] = (__bf16)a1.w;
      pb.e[0] = (__bf16)b0.x; pb.e[1] = (__bf16)b0.y; pb.e[2] = (__bf16)b0.z; pb.e[3] = (__bf16)b0.w;
      pb.e[4] = (__bf16)b1.x; pb.e[5] = (__bf16)b1.y; pb.e[6] = (__bf16)b1.z; pb.e[7] = (__bf16)b1.w;
      *(s16x8*)(&At[row * 32 + off0]) = pa.v;
      *(s16x8*)(&Bt[row * 32 + off0]) = pb.v;
    }
    __syncthreads();
    s16x8 af[4], bfr[4];
    for (int m = 0; m < 4; ++m)
      af[m] = *(const s16x8*)(&At[(wr * 64 + m * 16 + l15) * 32 + l4 * 8]);
    for (int nn = 0; nn < 4; ++nn)
      bfr[nn] = *(const s16x8*)(&Bt[(wc * 64 + nn * 16 + l15) * 32 + l4 * 8]);
    for (int m = 0; m < 4; ++m)
      for (int nn = 0; nn < 4; ++nn)
        acc[m][nn] = __builtin_amdgcn_mfma_f32_16x16x32_bf16(af[m], bfr[nn], acc[m][nn], 0, 0, 0);
    __syncthreads();
  }

  for (int m = 0; m < 4; ++m) {
    int row0 = by * 128 + wr * 64 + m * 16 + l4 * 4;
    for (int nn = 0; nn < 4; ++nn) {
      int col = bx * 128 + wc * 64 + nn * 16 + l15;
      float bc = biasRow ? 0.f : bias[col];
      for (int r = 0; r < 4; ++r) {
        int row = row0 + r;
        float v = acc[m][nn][r] + (biasRow ? bias[row] : bc);
        C[(size_t)row * N + col] = (__bf16)v;
      }
    }
  }
}

// ---------- out-proj GEMM: out = gelu(X[M][256] @ Wm[256][256]^T + bm), fp32
__global__ __launch_bounds__(256) void gemm_out(
    const __bf16* __restrict__ A, const float* __restrict__ Bw,
    const float* __restrict__ bias, float* __restrict__ C, int N)
{
  __shared__ __bf16 At[128 * 32];
  __shared__ __bf16 Bt[128 * 32];
  const int t = threadIdx.x;
  const int lane = t & 63, w = t >> 6;
  const int wr = w >> 1, wc = w & 1;
  const int l15 = lane & 15, l4 = lane >> 4;
  const int by = blockIdx.x, bx = blockIdx.y;

  f32x4 acc[4][4];
  for (int m = 0; m < 4; ++m)
    for (int nn = 0; nn < 4; ++nn) acc[m][nn] = (f32x4){0.f, 0.f, 0.f, 0.f};

  for (int kk = 0; kk < 256; kk += 32) {
    for (int j = 0; j < 2; ++j) {
      int c = t + j * 256;
      int row = c >> 2, off0 = (c & 3) * 8;
      *(s16x8*)(&At[row * 32 + off0]) =
          *(const s16x8*)(A + (size_t)(by * 128 + row) * 256 + kk + off0);
      const float* bp = Bw + (size_t)(bx * 128 + row) * 256 + kk + off0;
      float4 b0 = *(const float4*)bp, b1 = *(const float4*)(bp + 4);
      union { s16x8 v; __bf16 e[8]; } pb;
      pb.e[0] = (__bf16)b0.x; pb.e[1] = (__bf16)b0.y; pb.e[2] = (__bf16)b0.z; pb.e[3] = (__bf16)b0.w;
      pb.e[4] = (__bf16)b1.x; pb.e[5] = (__bf16)b1.y; pb.e[6] = (__bf16)b1.z; pb.e[7] = (__bf16)b1.w;
      *(s16x8*)(&Bt[row * 32 + off0]) = pb.v;
    }
    __syncthreads();
    s16x8 af[4], bfr[4];
    for (int m = 0; m < 4; ++m)
      af[m] = *(const s16x8*)(&At[(wr * 64 + m * 16 + l15) * 32 + l4 * 8]);
    for (int nn = 0; nn < 4; ++nn)
      bfr[nn] = *(const s16x8*)(&Bt[(wc * 64 + nn * 16 + l15) * 32 + l4 * 8]);
    for (int m = 0; m < 4; ++m)
      for (int nn = 0; nn < 4; ++nn)
        acc[m][nn] = __builtin_amdgcn_mfma_f32_16x16x32_bf16(af[m], bfr[nn], acc[m][nn], 0, 0, 0);
    __syncthreads();
  }

  for (int m = 0; m < 4; ++m) {
    int row0 = by * 128 + wr * 64 + m * 16 + l4 * 4;
    for (int nn = 0; nn < 4; ++nn) {
      int col = bx * 128 + wc * 64 + nn * 16 + l15;
      float bc = bias[col];
      for (int r = 0; r < 4; ++r) {
        int row = row0 + r;
        float v = acc[m][nn][r] + bc;
        v = 0.5f * v * (1.0f + erff(v * 0.70710678f));
        C[(size_t)row * N + col] = v;
      }
    }
  }
}

// ---------- attention: X = softmax(Q K^T / 16, key-masked) V --------------
// 1 block per graph, 512 thr (8 waves). Klds staged once; Plds reuses Klds
// space after a barrier. Wave w: QK^T+softmax for q rows [w*16,w*16+16);
// PV for d cols [w*32,w*32+32) over ALL q rows. X written into BQ in-place.
#define KSTR 264
#define PSTR 136
__global__ __launch_bounds__(512, 2) void attn_kernel(
    const __bf16* __restrict__ Q, const __bf16* __restrict__ Km,
    const __bf16* __restrict__ Vt, __bf16* __restrict__ X,
    const int* __restrict__ offs, int total)
{
  __shared__ __bf16 smem[128 * KSTR];                 // 67.6 KB, K then P
  __bf16 (*Klds)[KSTR] = (__bf16(*)[KSTR])smem;
  __bf16 (*Plds)[PSTR] = (__bf16(*)[PSTR])smem;

  const int g = blockIdx.x;
  const int off = offs[g];
  const int n = offs[g + 1] - off;
  const int t = threadIdx.x, lane = t & 63, w = t >> 6;
  const int l15 = lane & 15, l4 = lane >> 4;
  const bool qact = (w * 16) < n;

  // ---- stage K rows 0..127 (overrun beyond n reads valid ws, masked later)
  uint4 kst[8];
  #pragma unroll
  for (int j = 0; j < 8; ++j) {
    int row = j * 16 + (t >> 5);
    kst[j] = *(const uint4*)((const char*)(Km + (size_t)(off + row) * 256) + (t & 31) * 16);
  }
  // ---- Q frags for this wave's 16 rows
  s16x8 qf[8];
  if (qact) {
    int qr = w * 16 + l15; if (qr >= n) qr = n - 1;
    const __bf16* qp = Q + (size_t)(off + qr) * 256 + l4 * 8;
    #pragma unroll
    for (int kk = 0; kk < 8; ++kk) qf[kk] = *(const s16x8*)(qp + kk * 32);
  }
  #pragma unroll
  for (int j = 0; j < 8; ++j) {
    int row = j * 16 + (t >> 5);
    *(uint4*)((char*)&Klds[row][0] + (t & 31) * 16) = kst[j];
  }
  __syncthreads();

  // ---- S = Q K^T (from Klds)
  f32x4 sacc[8];
  #pragma unroll
  for (int i = 0; i < 8; ++i) sacc[i] = (f32x4){0.f, 0.f, 0.f, 0.f};
  if (qact) {
    #pragma unroll
    for (int kt = 0; kt < 8; ++kt) {
      if (kt * 16 < n) {
        const __bf16* kp = &Klds[kt * 16 + l15][l4 * 8];
        #pragma unroll
        for (int kk = 0; kk < 8; ++kk) {
          s16x8 kf = *(const s16x8*)(kp + kk * 32);
          sacc[kt] = __builtin_amdgcn_mfma_f32_16x16x32_bf16(qf[kk], kf, sacc[kt], 0, 0, 0);
        }
      }
    }
  }
  __syncthreads();                                    // Klds reads complete

  // ---- softmax (registers) -> Plds (bf16)
  if (qact) {
    #pragma unroll
    for (int r = 0; r < 4; ++r) {
      float sv[8];
      float m = -1e30f;
      #pragma unroll
      for (int kt = 0; kt < 8; ++kt) {
        int key = kt * 16 + l15;
        float v = (key < n) ? sacc[kt][r] * 0.0625f : -1e30f;
        sv[kt] = v; m = fmaxf(m, v);
      }
      for (int o = 1; o < 16; o <<= 1) m = fmaxf(m, __shfl_xor(m, o));
      float p[8], sum = 0.f;
      #pragma unroll
      for (int kt = 0; kt < 8; ++kt) { p[kt] = __expf(sv[kt] - m); sum += p[kt]; }
      for (int o = 1; o < 16; o <<= 1) sum += __shfl_xor(sum, o);
      float inv = 1.f / sum;
      int q = w * 16 + l4 * 4 + r;
      #pragma unroll
      for (int kt = 0; kt < 8; ++kt)
        Plds[q][kt * 16 + l15] = (__bf16)(p[kt] * inv);   // masked keys -> 0
    }
  }
  __syncthreads();                                    // Plds complete

  // ---- PV: wave w computes X[all 128 q][d in w*32..w*32+32)
  const int dbase = w * 32;
  f32x4 xacc[2][8];
  #pragma unroll
  for (int dt = 0; dt < 2; ++dt)
    #pragma unroll
    for (int qm = 0; qm < 8; ++qm) xacc[dt][qm] = (f32x4){0.f, 0.f, 0.f, 0.f};

  #pragma unroll
  for (int dt = 0; dt < 2; ++dt) {
    int d = dbase + dt * 16 + l15;
    s16x8 vf[4];
    #pragma unroll
    for (int ks = 0; ks < 4; ++ks) {
      int kc = off + ks * 32 + l4 * 8;
      if (kc > total - 8) kc = total - 8;             // P=0 there; stays finite
      vf[ks] = *(const s16x8*)(Vt + (size_t)d * total + kc);
    }
    #pragma unroll
    for (int qm = 0; qm < 8; ++qm) {
      #pragma unroll
      for (int ks = 0; ks < 4; ++ks) {
        if (ks * 32 < n) {
          s16x8 pa = *(const s16x8*)(&Plds[qm * 16 + l15][ks * 32 + l4 * 8]);
          xacc[dt][qm] = __builtin_amdgcn_mfma_f32_16x16x32_bf16(pa, vf[ks], xacc[dt][qm], 0, 0, 0);
        }
      }
    }
  }

  // ---- store X (bf16) rows q<n
  #pragma unroll
  for (int dt = 0; dt < 2; ++dt)
    #pragma unroll
    for (int qm = 0; qm < 8; ++qm)
      #pragma unroll
      for (int r = 0; r < 4; ++r) {
        int q = qm * 16 + l4 * 4 + r;
        if (q < n)
          X[(size_t)(off + q) * 256 + dbase + dt * 16 + l15] = (__bf16)xacc[dt][qm][r];
      }
}

// ---------------------------------------------------------------------------
extern "C" void kernel_launch(void* const* d_in, const int* in_sizes, int n_in,
                              void* d_out, int out_size, void* d_ws, size_t ws_size,
                              hipStream_t stream) {
  const float* rep2d = (const float*)d_in[0];
  const float* rep3d = (const float*)d_in[1];
  const int*   na    = (const int*)d_in[2];
  const float* wq23 = (const float*)d_in[3];  const float* bq23 = (const float*)d_in[4];
  const float* wk23 = (const float*)d_in[5];  const float* bk23 = (const float*)d_in[6];
  const float* wv23 = (const float*)d_in[7];  const float* bv23 = (const float*)d_in[8];
  const float* wq32 = (const float*)d_in[9];  const float* bq32 = (const float*)d_in[10];
  const float* wk32 = (const float*)d_in[11]; const float* bk32 = (const float*)d_in[12];
  const float* wv32 = (const float*)d_in[13]; const float* bv32 = (const float*)d_in[14];
  const float* wm23 = (const float*)d_in[15]; const float* bm23 = (const float*)d_in[16];
  const float* wm32 = (const float*)d_in[17]; const float* bm32 = (const float*)d_in[18];

  const int B = in_sizes[2];
  const int total = in_sizes[0] / 256;           // 40960
  float* out = (float*)d_out;

  char* ws = (char*)d_ws;
  const size_t SZ = (size_t)total * 256 * sizeof(__bf16);  // 20.97 MB
  const size_t need = 8192 + 3 * SZ;                       // 62.9 MB (proven ok)
  if (ws_size < need) {
    sentinel_kernel<<<1, 64, 0, stream>>>(out, 54321.0f);
    return;
  }
  int*    offs = (int*)ws;
  __bf16* BQ = (__bf16*)(ws + 8192);             // Q, then X in-place
  __bf16* BK = (__bf16*)(ws + 8192 + SZ);
  __bf16* BV = (__bf16*)(ws + 8192 + 2 * SZ);    // transposed V [256][total]

  scan_kernel<<<1, 64, 0, stream>>>(na, offs, B, total, out);

  dim3 blk(256);
  dim3 gP(total / 128, 2);   // [total,256] gemms
  dim3 gV(2, total / 128);   // transposed-V gemm: M=256, N=total
  dim3 gA(B);                // attention: 1 block/graph
  dim3 blkA(512);

  // branch 2d -> 3d
  gemm_kernel<<<gP, blk, 0, stream>>>(rep2d, wq23, bq23, BQ, 256, 0);
  gemm_kernel<<<gP, blk, 0, stream>>>(rep3d, wk23, bk23, BK, 256, 0);
  gemm_kernel<<<gV, blk, 0, stream>>>(wv23, rep3d, bv23, BV, total, 1);
  attn_kernel<<<gA, blkA, 0, stream>>>(BQ, BK, BV, BQ, offs, total);
  gemm_out<<<gP, blk, 0, stream>>>(BQ, wm23, bm23, out, 256);

  // branch 3d -> 2d
  gemm_kernel<<<gP, blk, 0, stream>>>(rep3d, wq32, bq32, BQ, 256, 0);
  gemm_kernel<<<gP, blk, 0, stream>>>(rep2d, wk32, bk32, BK, 256, 0);
  gemm_kernel<<<gV, blk, 0, stream>>>(wv32, rep2d, bv32, BV, total, 1);
  attn_kernel<<<gA, blkA, 0, stream>>>(BQ, BK, BV, BQ, offs, total);
  gemm_out<<<gP, blk, 0, stream>>>(BQ, wm32, bm32, out + (size_t)total * 256, 256);
}